// Round 1
// baseline (115.337 us; speedup 1.0000x reference)
//
#include <hip/hip_runtime.h>

#define TSTEPS 8
#define GROUPSZ 128

__global__ __launch_bounds__(256) void snn_if_kernel(
    const float* __restrict__ x,
    const float* __restrict__ threshold,
    float* __restrict__ out,
    int plane4,       // (B*L*d)/4
    int d4,           // d/4
    int g4)           // GROUP/4
{
    int idx = blockIdx.x * blockDim.x + threadIdx.x;
    if (idx >= plane4) return;

    int c = (idx % d4) / g4;          // channel index (d4, g4 are powers of 2 -> AND/shift)
    float thr = threshold[c];

    const float4* __restrict__ xv = reinterpret_cast<const float4*>(x);
    float4* __restrict__ ov = reinterpret_cast<float4*>(out);

    // Load all T timesteps up front: 8 independent 16B loads in flight per lane.
    float4 xr[TSTEPS];
    #pragma unroll
    for (int t = 0; t < TSTEPS; ++t)
        xr[t] = xv[(size_t)t * plane4 + idx];

    // Membrane potentials, pre-charged to thr/2 (pos and neg neuron).
    float vp[4], vn[4];
    #pragma unroll
    for (int j = 0; j < 4; ++j) { vp[j] = 0.5f * thr; vn[j] = 0.5f * thr; }

    #pragma unroll
    for (int t = 0; t < TSTEPS; ++t) {
        float xa[4] = { xr[t].x, xr[t].y, xr[t].z, xr[t].w };
        float oa[4];
        #pragma unroll
        for (int j = 0; j < 4; ++j) {
            // pos neuron: h = +x
            vp[j] += xa[j];
            float sp = (vp[j] >= thr) ? 1.0f : 0.0f;
            vp[j] -= sp * thr;
            // neg neuron: h = -x
            vn[j] -= xa[j];
            float sn = (vn[j] >= thr) ? 1.0f : 0.0f;
            vn[j] -= sn * thr;
            // fc2 recombine + rescale
            oa[j] = (sp - sn) * thr;
        }
        ov[(size_t)t * plane4 + idx] = make_float4(oa[0], oa[1], oa[2], oa[3]);
    }
}

extern "C" void kernel_launch(void* const* d_in, const int* in_sizes, int n_in,
                              void* d_out, int out_size, void* d_ws, size_t ws_size,
                              hipStream_t stream) {
    const float* x         = (const float*)d_in[0];
    const float* threshold = (const float*)d_in[1];
    float* out             = (float*)d_out;

    int total  = in_sizes[0];       // T*B*L*d
    int C      = in_sizes[1];       // number of channel groups
    int d      = C * GROUPSZ;
    int plane  = total / TSTEPS;    // B*L*d (elements per timestep)
    int plane4 = plane / 4;
    int d4     = d / 4;
    int g4     = GROUPSZ / 4;

    int block = 256;
    int grid  = (plane4 + block - 1) / block;
    snn_if_kernel<<<grid, block, 0, stream>>>(x, threshold, out, plane4, d4, g4);
}

// Round 3
// 111.995 us; speedup vs baseline: 1.0298x; 1.0298x over previous
//
#include <hip/hip_runtime.h>

#define TSTEPS 8
#define GROUPSZ 128

typedef float f32x4 __attribute__((ext_vector_type(4)));

__global__ __launch_bounds__(256) void snn_if_kernel(
    const float* __restrict__ x,
    const float* __restrict__ threshold,
    float* __restrict__ out,
    int plane4,       // (B*L*d)/4
    int d4_mask,      // d/4 - 1   (d4 is pow2)
    int g4_shift)     // log2(GROUP/4)
{
    int tid    = blockIdx.x * blockDim.x + threadIdx.x;
    int stride = gridDim.x * blockDim.x;

    // stride is a multiple of d4 by construction (grid chosen in launcher),
    // so the channel index is invariant across grid-stride iterations.
    int c = (tid & d4_mask) >> g4_shift;
    float thr = threshold[c];
    float vinit = 0.5f * thr;

    const f32x4* __restrict__ xv = reinterpret_cast<const f32x4*>(x);
    f32x4* __restrict__ ov = reinterpret_cast<f32x4*>(out);

    for (int idx = tid; idx < plane4; idx += stride) {
        // Load all T timesteps up front: 8 independent NT 16B loads in flight.
        f32x4 xr[TSTEPS];
        #pragma unroll
        for (int t = 0; t < TSTEPS; ++t)
            xr[t] = __builtin_nontemporal_load(&xv[(size_t)t * plane4 + idx]);

        float vp[4], vn[4];
        #pragma unroll
        for (int j = 0; j < 4; ++j) { vp[j] = vinit; vn[j] = vinit; }

        #pragma unroll
        for (int t = 0; t < TSTEPS; ++t) {
            f32x4 oa;
            #pragma unroll
            for (int j = 0; j < 4; ++j) {
                float xj = xr[t][j];
                // pos neuron: h = +x
                vp[j] += xj;
                float sp = (vp[j] >= thr) ? 1.0f : 0.0f;
                vp[j] -= sp * thr;
                // neg neuron: h = -x
                vn[j] -= xj;
                float sn = (vn[j] >= thr) ? 1.0f : 0.0f;
                vn[j] -= sn * thr;
                // fc2 recombine + rescale by threshold
                oa[j] = (sp - sn) * thr;
            }
            __builtin_nontemporal_store(oa, &ov[(size_t)t * plane4 + idx]);
        }
    }
}

extern "C" void kernel_launch(void* const* d_in, const int* in_sizes, int n_in,
                              void* d_out, int out_size, void* d_ws, size_t ws_size,
                              hipStream_t stream) {
    const float* x         = (const float*)d_in[0];
    const float* threshold = (const float*)d_in[1];
    float* out             = (float*)d_out;

    int total  = in_sizes[0];       // T*B*L*d
    int C      = in_sizes[1];       // number of channel groups
    int d      = C * GROUPSZ;
    int plane  = total / TSTEPS;    // B*L*d (elements per timestep)
    int plane4 = plane / 4;
    int d4     = d / 4;             // 1024 (pow2)
    int g4     = GROUPSZ / 4;       // 32   (pow2)

    int g4_shift = 0;
    while ((1 << g4_shift) < g4) ++g4_shift;

    int block = 256;
    // Cap grid at 2048 blocks, grid-stride the rest (G11). 2048*256 = 524288
    // is a multiple of d4=1024, keeping the channel index loop-invariant.
    int grid = (plane4 + block - 1) / block;
    if (grid > 2048) grid = 2048;

    snn_if_kernel<<<grid, block, 0, stream>>>(x, threshold, out,
                                              plane4, d4 - 1, g4_shift);
}

// Round 4
// 85.517 us; speedup vs baseline: 1.3487x; 1.3096x over previous
//
#include <hip/hip_runtime.h>

#define TSTEPS 8
#define GROUPSZ 128

typedef float f32x4 __attribute__((ext_vector_type(4)));

__global__ __launch_bounds__(256) void snn_if_kernel(
    const float* __restrict__ x,
    const float* __restrict__ threshold,
    float* __restrict__ out,
    int plane4,       // (B*L*d)/4
    int d4_mask,      // d/4 - 1   (d4 is pow2)
    int g4_shift)     // log2(GROUP/4)
{
    int tid    = blockIdx.x * blockDim.x + threadIdx.x;
    int stride = gridDim.x * blockDim.x;

    // stride is a multiple of d4 by construction (grid chosen in launcher),
    // so the channel index is invariant across grid-stride iterations.
    int c = (tid & d4_mask) >> g4_shift;
    float thr = threshold[c];
    float vinit = 0.5f * thr;

    const f32x4* __restrict__ xv = reinterpret_cast<const f32x4*>(x);
    f32x4* __restrict__ ov = reinterpret_cast<f32x4*>(out);

    for (int idx = tid; idx < plane4; idx += stride) {
        // x: PLAIN loads -> allocate in L2/L3. x is exactly 256 MiB = L3 size;
        // it stays LLC-resident across graph replays (out is NT, below).
        f32x4 xr[TSTEPS];
        #pragma unroll
        for (int t = 0; t < TSTEPS; ++t)
            xr[t] = xv[(size_t)t * plane4 + idx];

        float vp[4], vn[4];
        #pragma unroll
        for (int j = 0; j < 4; ++j) { vp[j] = vinit; vn[j] = vinit; }

        #pragma unroll
        for (int t = 0; t < TSTEPS; ++t) {
            f32x4 oa;
            #pragma unroll
            for (int j = 0; j < 4; ++j) {
                float xj = xr[t][j];
                // pos neuron: h = +x
                vp[j] += xj;
                float sp = (vp[j] >= thr) ? 1.0f : 0.0f;
                vp[j] -= sp * thr;
                // neg neuron: h = -x
                vn[j] -= xj;
                float sn = (vn[j] >= thr) ? 1.0f : 0.0f;
                vn[j] -= sn * thr;
                // fc2 recombine + rescale by threshold
                oa[j] = (sp - sn) * thr;
            }
            // out: NT stores -> no LLC allocation, don't evict x.
            __builtin_nontemporal_store(oa, &ov[(size_t)t * plane4 + idx]);
        }
    }
}

extern "C" void kernel_launch(void* const* d_in, const int* in_sizes, int n_in,
                              void* d_out, int out_size, void* d_ws, size_t ws_size,
                              hipStream_t stream) {
    const float* x         = (const float*)d_in[0];
    const float* threshold = (const float*)d_in[1];
    float* out             = (float*)d_out;

    int total  = in_sizes[0];       // T*B*L*d
    int C      = in_sizes[1];       // number of channel groups
    int d      = C * GROUPSZ;
    int plane  = total / TSTEPS;    // B*L*d (elements per timestep)
    int plane4 = plane / 4;
    int d4     = d / 4;             // 1024 (pow2)
    int g4     = GROUPSZ / 4;       // 32   (pow2)

    int g4_shift = 0;
    while ((1 << g4_shift) < g4) ++g4_shift;

    int block = 256;
    // 2048 blocks = 8 blocks/CU exactly; 524288 threads -> 4 grid-stride
    // iterations, stride is a multiple of d4=1024 (channel loop-invariant).
    int grid = (plane4 + block - 1) / block;
    if (grid > 2048) grid = 2048;

    snn_if_kernel<<<grid, block, 0, stream>>>(x, threshold, out,
                                              plane4, d4 - 1, g4_shift);
}